// Round 1
// baseline (15.224 us; speedup 1.0000x reference)
//
#include <hip/hip_runtime.h>
#include <math.h>

// GATLayer fused kernel, MI355X (gfx950).
//
// Reference simplifications exploited:
//  - receivers == senders  =>  spatial_relations == 0  =>  spatial_embed == b_sp (W_sp dead)
//  - rel_rec / rel_send are one-hot (i,j) i!=j enumerations => all their matmuls are gathers
//  - attention(n,m) = lrelu(s_n + s_m + c), s_n = c0 + x_n . (W_node @ w_att)  (F=4 dot)
//  - A diag = 0 (no self edge), softmax over all 64 incl. the 0
//  - out[b,t,n,:] = lrelu( sum_m softmaxrow(n)[m] * ne[b,m,t,:] )
//
// One block per (b,t): 4 waves x 64 lanes; wave owns 16 output rows; lane = d (or m).

namespace {

constexpr int Bb = 8, Nn = 64, Tt = 30, Ff = 4, Dd = 64;

__device__ __forceinline__ float lane_bcast(float v, int l) {
    return __int_as_float(__builtin_amdgcn_readlane(__float_as_int(v), l));
}

__global__ __launch_bounds__(256) void gat_fused(
    const float* __restrict__ x,     // [B][N][T][F]
    const float* __restrict__ Wn,    // [F][D]
    const float* __restrict__ bn,    // [D]
    const float* __restrict__ bsp,   // [D]
    const float* __restrict__ watt,  // [D]
    const float* __restrict__ batt,  // [1]
    float* __restrict__ out)         // [B][T][N][D]
{
    __shared__ float xs[Nn][Ff];   // 1 KB   x[b, :, t, :]
    __shared__ float ne[Nn][Dd];   // 16 KB  nodes_embed[b, :, t, :]

    const int tid  = threadIdx.x;
    const int lane = tid & 63;
    const int wave = tid >> 6;
    const int bt   = blockIdx.x;
    const int b    = bt / Tt;
    const int t    = bt - b * Tt;

    // cooperative x tile load: thread -> (n = tid/4, f = tid%4)
    {
        const int n = tid >> 2, f = tid & 3;
        xs[n][f] = x[(((size_t)b * Nn + n) * Tt + t) * Ff + f];
    }

    // per-lane weight columns (lane = d)
    const float w0 = Wn[0 * Dd + lane], w1 = Wn[1 * Dd + lane],
                w2 = Wn[2 * Dd + lane], w3 = Wn[3 * Dd + lane];
    const float bnd = bn[lane];
    const float wa  = watt[lane];

    // butterfly reductions: Wwa[f] = sum_d Wn[f][d]*wa[d]; c0 = bn.wa; c1 = bsp.wa
    float r0 = w0 * wa, r1 = w1 * wa, r2 = w2 * wa, r3 = w3 * wa,
          r4 = bnd * wa, r5 = bsp[lane] * wa;
    #pragma unroll
    for (int off = 32; off >= 1; off >>= 1) {
        r0 += __shfl_xor(r0, off, 64);
        r1 += __shfl_xor(r1, off, 64);
        r2 += __shfl_xor(r2, off, 64);
        r3 += __shfl_xor(r3, off, 64);
        r4 += __shfl_xor(r4, off, 64);
        r5 += __shfl_xor(r5, off, 64);
    }
    const float cadd = r5 + batt[0];   // bsp.w_att + b_att

    __syncthreads();   // xs ready

    // per-lane attention score: s_l = score of node (lane)
    const float4 xl = *reinterpret_cast<const float4*>(&xs[lane][0]);
    const float s_l = r4 + xl.x * r0 + xl.y * r1 + xl.z * r2 + xl.w * r3;

    // nodes_embed: wave w computes rows n = 16w..16w+15, lane = d
    #pragma unroll
    for (int k = 0; k < 16; ++k) {
        const int n = wave * 16 + k;
        const float x0 = xs[n][0], x1 = xs[n][1], x2 = xs[n][2], x3 = xs[n][3];
        ne[n][lane] = bnd + x0 * w0 + x1 * w1 + x2 * w2 + x3 * w3;
    }
    __syncthreads();   // ne ready

    // cache my ne column: col[m] = ne[m][lane]  (64 VGPRs, conflict-free reads)
    float col[64];
    #pragma unroll
    for (int m = 0; m < 64; ++m) col[m] = ne[m][lane];

    // attention rows + softmax, lane-distributed (lane = m), kept in registers
    float p[16];
    #pragma unroll
    for (int k = 0; k < 16; ++k) {
        const int n  = wave * 16 + k;
        const float sn = lane_bcast(s_l, n);
        const float v  = sn + s_l + cadd;
        float a = (lane == n) ? 0.0f : ((v > 0.0f) ? v : 0.01f * v);  // lrelu, diag=0
        float mx = a;
        #pragma unroll
        for (int off = 32; off >= 1; off >>= 1)
            mx = fmaxf(mx, __shfl_xor(mx, off, 64));
        const float e = expf(a - mx);
        float se = e;
        #pragma unroll
        for (int off = 32; off >= 1; off >>= 1)
            se += __shfl_xor(se, off, 64);
        p[k] = e / se;
    }

    // out rows: acc[k] = sum_m A[n_k][m] * ne[m][lane]; A row broadcast via v_readlane
    float acc[16];
    #pragma unroll
    for (int k = 0; k < 16; ++k) acc[k] = 0.0f;
    #pragma unroll
    for (int m = 0; m < 64; ++m) {
        const float cm = col[m];
        #pragma unroll
        for (int k = 0; k < 16; ++k)
            acc[k] = fmaf(lane_bcast(p[k], m), cm, acc[k]);
    }

    float* op = out + (((size_t)b * Tt + t) * Nn + wave * 16) * Dd + lane;
    #pragma unroll
    for (int k = 0; k < 16; ++k) {
        const float a = acc[k];
        op[k * Dd] = (a > 0.0f) ? a : 0.01f * a;   // final leaky_relu
    }
}

} // namespace

extern "C" void kernel_launch(void* const* d_in, const int* in_sizes, int n_in,
                              void* d_out, int out_size, void* d_ws, size_t ws_size,
                              hipStream_t stream) {
    const float* x    = (const float*)d_in[0];
    // d_in[1] rel_rec, d_in[2] rel_send: one-hot structure known at compile time, unused
    const float* Wn   = (const float*)d_in[3];
    const float* bn   = (const float*)d_in[4];
    // d_in[5] W_sp: dead (spatial_relations == 0)
    const float* bsp  = (const float*)d_in[6];
    const float* watt = (const float*)d_in[7];
    const float* batt = (const float*)d_in[8];
    float* out = (float*)d_out;

    gat_fused<<<dim3(Bb * Tt), dim3(256), 0, stream>>>(x, Wn, bn, bsp, watt, batt, out);
}

// Round 2
// 13.220 us; speedup vs baseline: 1.1516x; 1.1516x over previous
//
#include <hip/hip_runtime.h>
#include <math.h>

// GATLayer fused kernel v2, MI355X (gfx950).
//
// Math simplifications (verified in R0):
//  - receivers == senders => spatial_embed == b_sp (W_sp dead)
//  - rel_rec/rel_send one-hot => A[n][m] = lrelu(s_n + s_m + c) for n!=m, 0 on diag
//  - s_n = (bn.wa) + x_n . (Wn @ wa)   (F=4 dot), c = bsp.wa + b_att
//  - softmax needs no max-subtraction: scores bounded ~[0,5], exp safe in fp32
//  - out[n][d] = rse_n * lrelu( sum_m E[n][m] * ne[m][d] ),  E = exp(score), diag E=1
//
// v2 changes vs v1 (latency-bound fix):
//  - 480 blocks (2 per (b,t), rows split 32/32) -> 2 waves/SIMD TLP, half matmul pole
//  - softmax stats lane-distributed (lane = 16*mquarter + rowlocal): zero butterfly
//    chains except one 2-step se-combine; E staged in LDS [64][65] (2-way banks = free)
//  - __expf / v_rcp_f32 / fmaxf-lrelu instead of libm expf + precise div

namespace {

constexpr int Bb = 8, Nn = 64, Tt = 30, Ff = 4, Dd = 64;

__device__ __forceinline__ float lane_bcast(float v, int l) {
    return __int_as_float(__builtin_amdgcn_readlane(__float_as_int(v), l));
}

__global__ __launch_bounds__(256) void gat_fused(
    const float* __restrict__ x,     // [B][N][T][F]
    const float* __restrict__ Wn,    // [F][D]
    const float* __restrict__ bn,    // [D]
    const float* __restrict__ bsp,   // [D]
    const float* __restrict__ watt,  // [D]
    const float* __restrict__ batt,  // [1]
    float* __restrict__ out)         // [B][T][N][D]
{
    __shared__ float xs[Nn][Ff];      // 1 KB    x[b, :, t, :]
    __shared__ float ne[Nn][Dd];      // 16 KB   nodes_embed[b, :, t, :]
    __shared__ float E[Nn][Nn + 1];   // 16.25KB exp(scores), +1 pad (2-way banks)
    __shared__ float sh_s[Nn];        // node attention scalars
    __shared__ float sh_rse[Nn];      // 1/softmax-denominator per row

    const int tid  = threadIdx.x;
    const int lane = tid & 63;
    const int wave = tid >> 6;
    const int blk  = blockIdx.x;
    const int bt   = blk >> 1;
    const int half = blk & 1;
    const int b    = bt / Tt;
    const int t    = bt - b * Tt;

    // cooperative x tile load: thread -> (n = tid/4, f = tid%4)
    {
        const int n = tid >> 2, f = tid & 3;
        xs[n][f] = x[(((size_t)b * Nn + n) * Tt + t) * Ff + f];
    }

    // per-lane weight columns (lane = d)
    const float w0 = Wn[0 * Dd + lane], w1 = Wn[1 * Dd + lane],
                w2 = Wn[2 * Dd + lane], w3 = Wn[3 * Dd + lane];
    const float bnd = bn[lane];
    const float wa  = watt[lane];

    // one-time butterflies: r0..r3 = Wn@wa, r4 = bn.wa, r5 = bsp.wa
    float r0 = w0 * wa, r1 = w1 * wa, r2 = w2 * wa, r3 = w3 * wa,
          r4 = bnd * wa, r5 = bsp[lane] * wa;
    #pragma unroll
    for (int off = 32; off >= 1; off >>= 1) {
        r0 += __shfl_xor(r0, off, 64);
        r1 += __shfl_xor(r1, off, 64);
        r2 += __shfl_xor(r2, off, 64);
        r3 += __shfl_xor(r3, off, 64);
        r4 += __shfl_xor(r4, off, 64);
        r5 += __shfl_xor(r5, off, 64);
    }
    const float cadd = r5 + batt[0];   // bsp.w_att + b_att

    __syncthreads();   // xs ready

    // node scores (wave 0 only; consumed via LDS after next barrier)
    if (wave == 0) {
        const float4 xl = *reinterpret_cast<const float4*>(&xs[lane][0]);
        sh_s[lane] = r4 + xl.x * r0 + xl.y * r1 + xl.z * r2 + xl.w * r3;
    }

    // nodes_embed: wave w computes rows n = 16w..16w+15, lane = d
    #pragma unroll
    for (int k = 0; k < 16; ++k) {
        const int n = wave * 16 + k;
        const float4 xn = *reinterpret_cast<const float4*>(&xs[n][0]);
        ne[n][lane] = bnd + xn.x * w0 + xn.y * w1 + xn.z * w2 + xn.w * w3;
    }
    __syncthreads();   // ne, sh_s ready

    // cache my ne column: col[m] = ne[m][lane]  (2-way banks = free)
    float col[64];
    #pragma unroll
    for (int m = 0; m < 64; ++m) col[m] = ne[m][lane];

    // softmax stats, no max-subtraction. wave w owns rows w*16..w*16+15;
    // lane = (mq<<4)|rl: row r = w*16+rl, m-quarter mq covers m = 16mq..16mq+15.
    {
        const int rl = lane & 15, mq = lane >> 4;
        const int r  = wave * 16 + rl;
        const float srow = sh_s[r];
        float se = 0.0f;
        #pragma unroll
        for (int i = 0; i < 16; ++i) {
            const int m = mq * 16 + i;
            const float sm = sh_s[m];
            const float v  = srow + sm + cadd;
            float e = __expf(fmaxf(v, 0.01f * v));   // exp(lrelu(v))
            e = (m == r) ? 1.0f : e;                 // diag score is 0 -> exp = 1
            E[r][m] = e;
            se += e;
        }
        se += __shfl_xor(se, 16, 64);
        se += __shfl_xor(se, 32, 64);
        if (lane < 16) sh_rse[wave * 16 + lane] = __builtin_amdgcn_rcpf(se);
    }
    __syncthreads();   // E, sh_rse ready

    // matmul: this block's rows n_k = half*32 + wave*8 + k, k = 0..7; lane = d
    float pr[8], rs[8], acc[8];
    #pragma unroll
    for (int k = 0; k < 8; ++k) {
        const int n = half * 32 + wave * 8 + k;
        pr[k]  = E[n][lane];      // lane holds E[n][lane]; broadcast via readlane
        rs[k]  = sh_rse[n];
        acc[k] = 0.0f;
    }
    #pragma unroll
    for (int m = 0; m < 64; ++m) {
        const float cm = col[m];
        #pragma unroll
        for (int k = 0; k < 8; ++k)
            acc[k] = fmaf(lane_bcast(pr[k], m), cm, acc[k]);
    }

    float* op = out + (((size_t)b * Tt + t) * Nn + half * 32 + wave * 8) * Dd + lane;
    #pragma unroll
    for (int k = 0; k < 8; ++k) {
        const float z = acc[k];
        op[k * Dd] = rs[k] * fmaxf(z, 0.01f * z);   // lrelu then 1/se scale
    }
}

} // namespace

extern "C" void kernel_launch(void* const* d_in, const int* in_sizes, int n_in,
                              void* d_out, int out_size, void* d_ws, size_t ws_size,
                              hipStream_t stream) {
    const float* x    = (const float*)d_in[0];
    // d_in[1] rel_rec, d_in[2] rel_send: one-hot, folded into indexing (unused)
    const float* Wn   = (const float*)d_in[3];
    const float* bn   = (const float*)d_in[4];
    // d_in[5] W_sp: dead (spatial_relations == 0)
    const float* bsp  = (const float*)d_in[6];
    const float* watt = (const float*)d_in[7];
    const float* batt = (const float*)d_in[8];
    float* out = (float*)d_out;

    gat_fused<<<dim3(Bb * Tt * 2), dim3(256), 0, stream>>>(x, Wn, bn, bsp, watt, batt, out);
}